// Round 3
// baseline (400.389 us; speedup 1.0000x reference)
//
#include <hip/hip_runtime.h>

// Problem constants: B=2, L=2048, NH=8, DH=64, DM=512, TEMP=8.
// Outputs (concat fp32): qh (2,8,2048,64) then attn (2,8,2048,2048).

typedef __attribute__((ext_vector_type(8))) short bf16x8_t;   // MFMA A/B frag
typedef __attribute__((ext_vector_type(4))) float f32x4_t;    // MFMA C/D frag
typedef __attribute__((ext_vector_type(4))) short s16x4_t;

#define MFMA16(a, b, c) __builtin_amdgcn_mfma_f32_16x16x32_bf16((a), (b), (c), 0, 0, 0)

__device__ __forceinline__ short f2bf(float x) {
    union { float f; unsigned u; } v; v.f = x;
    unsigned r = v.u + 0x7fffu + ((v.u >> 16) & 1u);
    return (short)(r >> 16);
}

// ---------------------------------------------------------------------------
// Kernel 0: fp32 -> bf16 convert of q, k, Wq, Wk — each element exactly once.
// ---------------------------------------------------------------------------
__global__ __launch_bounds__(256) void cvt_kernel(
    const float* __restrict__ q, const float* __restrict__ k,
    const float* __restrict__ Wq, const float* __restrict__ Wk,
    short* __restrict__ qb, short* __restrict__ kb,
    short* __restrict__ Wqb, short* __restrict__ Wkb)
{
    const int NQ = 262144;   // 2*2048*512 / 8 vec8 chunks
    const int NW = 32768;    // 512*512 / 8
    for (int i = blockIdx.x * 256 + threadIdx.x; i < 2 * NQ + 2 * NW;
         i += gridDim.x * 256) {
        const float* src; short* dst; int off;
        if (i < NQ)               { src = q;  dst = qb;  off = i; }
        else if (i < 2 * NQ)      { src = k;  dst = kb;  off = i - NQ; }
        else if (i < 2 * NQ + NW) { src = Wq; dst = Wqb; off = i - 2 * NQ; }
        else                      { src = Wk; dst = Wkb; off = i - 2 * NQ - NW; }
        const float* p = src + (size_t)off * 8;
        f32x4_t lo = *(const f32x4_t*)p;
        f32x4_t hi = *(const f32x4_t*)(p + 4);
        bf16x8_t r;
        r[0] = f2bf(lo[0]); r[1] = f2bf(lo[1]); r[2] = f2bf(lo[2]); r[3] = f2bf(lo[3]);
        r[4] = f2bf(hi[0]); r[5] = f2bf(hi[1]); r[6] = f2bf(hi[2]); r[7] = f2bf(hi[3]);
        *(bf16x8_t*)(dst + (size_t)off * 8) = r;
    }
}

// ---------------------------------------------------------------------------
// Kernel 1: C = A @ W^T for A in {q,k} bf16 (4096x512), W bf16 (512x512).
// SWAPPED operands: mfma(W_frag, A_frag) -> D[n][m], so each lane's 4 acc
// components are 4 consecutive n (= head-dim d) of one output row -> f32x4
// stores (was: scalar dword scatter).
// ---------------------------------------------------------------------------
__global__ __launch_bounds__(256) void proj_kernel(
    const short* __restrict__ qb, const short* __restrict__ kb,
    const short* __restrict__ Wqb, const short* __restrict__ Wkb,
    float* __restrict__ qh_f32, short* __restrict__ qh_bf,
    short* __restrict__ kh_bf)
{
    const int z  = blockIdx.z;
    const short* A = z ? kb  : qb;
    const short* W = z ? Wkb : Wqb;
    const int m0 = blockIdx.x * 64;
    const int n0 = blockIdx.y * 128;
    const int tid  = threadIdx.x;
    const int wave = tid >> 6;
    const int lane = tid & 63;
    const int wm = (wave >> 1) * 32;
    const int wn = (wave & 1) * 64;
    const int lrow = lane & 15;
    const int lk   = (lane >> 4) * 8;

    f32x4_t acc[2][4] = {};

#pragma unroll 4
    for (int ks = 0; ks < 512; ks += 32) {
        bf16x8_t af[2], wf[4];
#pragma unroll
        for (int mt = 0; mt < 2; ++mt)
            af[mt] = *(const bf16x8_t*)(A + (size_t)(m0 + wm + mt * 16 + lrow) * 512 + ks + lk);
#pragma unroll
        for (int nt = 0; nt < 4; ++nt)
            wf[nt] = *(const bf16x8_t*)(W + (size_t)(n0 + wn + nt * 16 + lrow) * 512 + ks + lk);
#pragma unroll
        for (int mt = 0; mt < 2; ++mt)
#pragma unroll
            for (int nt = 0; nt < 4; ++nt)
                acc[mt][nt] = MFMA16(wf[nt], af[mt], acc[mt][nt]);  // D[n][m]
    }

    const int g4 = (lane >> 4) * 4;
#pragma unroll
    for (int mt = 0; mt < 2; ++mt) {
        const int m  = m0 + wm + mt * 16 + lrow;   // output row (b,l)
        const int bb = m >> 11;
        const int l  = m & 2047;
#pragma unroll
        for (int nt = 0; nt < 4; ++nt) {
            const int nb = n0 + wn + nt * 16 + g4;  // 4 consecutive n
            const int h  = nb >> 6;
            const int d  = nb & 63;                 // d..d+3 same head
            const size_t idx = ((size_t)(bb * 8 + h) * 2048 + l) * 64 + d;
            const f32x4_t v = acc[mt][nt];
            s16x4_t pb;
            pb[0] = f2bf(v[0]); pb[1] = f2bf(v[1]);
            pb[2] = f2bf(v[2]); pb[3] = f2bf(v[3]);
            if (z == 0) {
                *(f32x4_t*)(qh_f32 + idx) = v;
                *(s16x4_t*)(qh_bf + idx) = pb;
            } else {
                *(s16x4_t*)(kh_bf + idx) = pb;
            }
        }
    }
}

// ---------------------------------------------------------------------------
// Kernel 2a: row sums only -> rinv[b,h,row]. grid (64,16): x = 32-row q tile,
// y = (b,h). Swapped layout: lane sums its 4 keys locally, then 2 shuffles.
// ---------------------------------------------------------------------------
__global__ __launch_bounds__(256) void sum_kernel(
    const short* __restrict__ qh, const short* __restrict__ kh,
    const int* __restrict__ mask, float* __restrict__ rinv_g)
{
    const int q0 = blockIdx.x * 32;
    const int bh = blockIdx.y;
    const int b  = bh >> 3;
    const int tid = threadIdx.x;

    __shared__ float bias[2048];
    __shared__ float psum[4 * 32];

    for (int j = tid; j < 2048; j += 256)
        bias[j] = mask[b * 2048 + j] ? 0.f : -1e9f;
    __syncthreads();

    const int wave = tid >> 6;
    const int lane = tid & 63;
    const int lrow = lane & 15;
    const int lk   = (lane >> 4) * 8;
    const int g4   = (lane >> 4) * 4;

    const short* Qb = qh + (size_t)bh * 2048 * 64;
    const short* Kb = kh + (size_t)bh * 2048 * 64;

    bf16x8_t qf0[2], qf1[2];
#pragma unroll
    for (int rt = 0; rt < 2; ++rt) {
        const short* qp = Qb + (size_t)(q0 + rt * 16 + lrow) * 64 + lk;
        qf0[rt] = *(const bf16x8_t*)qp;
        qf1[rt] = *(const bf16x8_t*)(qp + 32);
    }

    const int k0 = wave * 512;
    float sum[2] = {0.f, 0.f};
#pragma unroll 4
    for (int kc = k0; kc < k0 + 512; kc += 16) {
        const short* kp = Kb + (size_t)(kc + lrow) * 64 + lk;
        const bf16x8_t ka = *(const bf16x8_t*)kp;
        const bf16x8_t kb2 = *(const bf16x8_t*)(kp + 32);
        const f32x4_t b4 = *(const f32x4_t*)&bias[kc + g4];
#pragma unroll
        for (int rt = 0; rt < 2; ++rt) {
            f32x4_t acc = {};
            acc = MFMA16(ka,  qf0[rt], acc);   // D[key][qrow]
            acc = MFMA16(kb2, qf1[rt], acc);
#pragma unroll
            for (int r = 0; r < 4; ++r)
                sum[rt] += __expf(fmaf(acc[r], 0.125f, b4[r]));
        }
    }
    // lane holds partial for qrow=lrow over its key-groups; fold groups:
#pragma unroll
    for (int rt = 0; rt < 2; ++rt) {
        sum[rt] += __shfl_xor(sum[rt], 16, 64);
        sum[rt] += __shfl_xor(sum[rt], 32, 64);
    }
    if (lane < 16) {
        psum[wave * 32 + lane]      = sum[0];
        psum[wave * 32 + 16 + lane] = sum[1];
    }
    __syncthreads();
    if (tid < 32)
        rinv_g[bh * 2048 + q0 + tid] =
            1.f / (psum[tid] + psum[32 + tid] + psum[64 + tid] + psum[96 + tid]);
}

// ---------------------------------------------------------------------------
// Kernel 2b: recompute scores, scale by rinv, f32x4 coalesced stores.
// grid (128,16): x = 16-row q tile, y = (b,h) -> 2048 blocks, 8 blocks/CU,
// full occupancy. One f32x4 store per lane per 16-key step: each store inst
// writes 16 rows x 64 B contiguous (1 KB/inst) instead of scattered dwords.
// ---------------------------------------------------------------------------
__global__ __launch_bounds__(256) void write_kernel(
    const short* __restrict__ qh, const short* __restrict__ kh,
    const int* __restrict__ mask, const float* __restrict__ rinv_g,
    float* __restrict__ attn)
{
    const int q0 = blockIdx.x * 16;
    const int bh = blockIdx.y;
    const int b  = bh >> 3;
    const int tid = threadIdx.x;

    __shared__ float bias[2048];

    for (int j = tid; j < 2048; j += 256)
        bias[j] = mask[b * 2048 + j] ? 0.f : -1e9f;
    __syncthreads();

    const int wave = tid >> 6;
    const int lane = tid & 63;
    const int lrow = lane & 15;
    const int lk   = (lane >> 4) * 8;
    const int g4   = (lane >> 4) * 4;

    const short* Qb = qh + (size_t)bh * 2048 * 64;
    const short* Kb = kh + (size_t)bh * 2048 * 64;

    const short* qp = Qb + (size_t)(q0 + lrow) * 64 + lk;
    const bf16x8_t qf0 = *(const bf16x8_t*)qp;
    const bf16x8_t qf1 = *(const bf16x8_t*)(qp + 32);
    const float rv = rinv_g[bh * 2048 + q0 + lrow];

    const int k0 = wave * 512;
    // lane's store base: its q row, its 4-key group
    float* orow = attn + ((size_t)bh * 2048 + q0 + lrow) * 2048 + g4;

#pragma unroll 4
    for (int kc = k0; kc < k0 + 512; kc += 16) {
        const short* kp = Kb + (size_t)(kc + lrow) * 64 + lk;
        const bf16x8_t ka = *(const bf16x8_t*)kp;
        const bf16x8_t kb2 = *(const bf16x8_t*)(kp + 32);
        const f32x4_t b4 = *(const f32x4_t*)&bias[kc + g4];
        f32x4_t acc = {};
        acc = MFMA16(ka,  qf0, acc);   // D[key][qrow]
        acc = MFMA16(kb2, qf1, acc);
        f32x4_t o;
#pragma unroll
        for (int r = 0; r < 4; ++r)
            o[r] = __expf(fmaf(acc[r], 0.125f, b4[r])) * rv;
        *(f32x4_t*)(orow + kc) = o;
    }
}

// ---------------------------------------------------------------------------
extern "C" void kernel_launch(void* const* d_in, const int* in_sizes, int n_in,
                              void* d_out, int out_size, void* d_ws, size_t ws_size,
                              hipStream_t stream)
{
    const float* q    = (const float*)d_in[0];
    const float* k    = (const float*)d_in[1];
    const int*   mask = (const int*)  d_in[3];
    const float* Wq   = (const float*)d_in[4];
    const float* Wk   = (const float*)d_in[5];

    float* out    = (float*)d_out;
    float* qh_f32 = out;                 // 2,097,152 floats
    float* attn   = out + 2097152;       // 67,108,864 floats

    short* qh_bf = (short*)d_ws;         // 4 MB
    short* kh_bf = qh_bf + 2097152;      // 4 MB
    float* rinv  = (float*)(kh_bf + 2097152);  // 128 KB

    // bf16 input scratch lives in the not-yet-written attn output region
    // (consumed by proj_kernel before attn writes start).
    short* qb  = (short*)attn;
    short* kb  = qb  + 2097152;
    short* Wqb = kb  + 2097152;
    short* Wkb = Wqb + 262144;

    cvt_kernel  <<<dim3(1024),     256, 0, stream>>>(q, k, Wq, Wk, qb, kb, Wqb, Wkb);
    proj_kernel <<<dim3(64, 4, 2), 256, 0, stream>>>(qb, kb, Wqb, Wkb, qh_f32, qh_bf, kh_bf);
    sum_kernel  <<<dim3(64, 16),   256, 0, stream>>>(qh_bf, kh_bf, mask, rinv);
    write_kernel<<<dim3(128, 16),  256, 0, stream>>>(qh_bf, kh_bf, mask, rinv, attn);
}

// Round 4
// 398.633 us; speedup vs baseline: 1.0044x; 1.0044x over previous
//
#include <hip/hip_runtime.h>

// Problem constants: B=2, L=2048, NH=8, DH=64, DM=512, TEMP=8.
// Outputs (concat fp32): qh (2,8,2048,64) then attn (2,8,2048,2048).

typedef __attribute__((ext_vector_type(8))) short bf16x8_t;   // MFMA A/B frag
typedef __attribute__((ext_vector_type(4))) float f32x4_t;    // MFMA C/D frag
typedef __attribute__((ext_vector_type(4))) short s16x4_t;

#define MFMA16(a, b, c) __builtin_amdgcn_mfma_f32_16x16x32_bf16((a), (b), (c), 0, 0, 0)

__device__ __forceinline__ short f2bf(float x) {
    union { float f; unsigned u; } v; v.f = x;
    unsigned r = v.u + 0x7fffu + ((v.u >> 16) & 1u);
    return (short)(r >> 16);
}

// ---------------------------------------------------------------------------
// Kernel 0: fp32 -> bf16 convert of q, k, Wq, Wk — each element exactly once.
// ---------------------------------------------------------------------------
__global__ __launch_bounds__(256) void cvt_kernel(
    const float* __restrict__ q, const float* __restrict__ k,
    const float* __restrict__ Wq, const float* __restrict__ Wk,
    short* __restrict__ qb, short* __restrict__ kb,
    short* __restrict__ Wqb, short* __restrict__ Wkb)
{
    const int NQ = 262144;   // 2*2048*512 / 8 vec8 chunks
    const int NW = 32768;    // 512*512 / 8
    for (int i = blockIdx.x * 256 + threadIdx.x; i < 2 * NQ + 2 * NW;
         i += gridDim.x * 256) {
        const float* src; short* dst; int off;
        if (i < NQ)               { src = q;  dst = qb;  off = i; }
        else if (i < 2 * NQ)      { src = k;  dst = kb;  off = i - NQ; }
        else if (i < 2 * NQ + NW) { src = Wq; dst = Wqb; off = i - 2 * NQ; }
        else                      { src = Wk; dst = Wkb; off = i - 2 * NQ - NW; }
        const float* p = src + (size_t)off * 8;
        f32x4_t lo = *(const f32x4_t*)p;
        f32x4_t hi = *(const f32x4_t*)(p + 4);
        bf16x8_t r;
        r[0] = f2bf(lo[0]); r[1] = f2bf(lo[1]); r[2] = f2bf(lo[2]); r[3] = f2bf(lo[3]);
        r[4] = f2bf(hi[0]); r[5] = f2bf(hi[1]); r[6] = f2bf(hi[2]); r[7] = f2bf(hi[3]);
        *(bf16x8_t*)(dst + (size_t)off * 8) = r;
    }
}

// ---------------------------------------------------------------------------
// Kernel 1: C = A @ W^T for A in {q,k} bf16 (4096x512), W bf16 (512x512).
// Swapped operands: D[n][m], lane's 4 acc = 4 consecutive head-dims -> f32x4.
// ---------------------------------------------------------------------------
__global__ __launch_bounds__(256) void proj_kernel(
    const short* __restrict__ qb, const short* __restrict__ kb,
    const short* __restrict__ Wqb, const short* __restrict__ Wkb,
    float* __restrict__ qh_f32, short* __restrict__ qh_bf,
    short* __restrict__ kh_bf)
{
    const int z  = blockIdx.z;
    const short* A = z ? kb  : qb;
    const short* W = z ? Wkb : Wqb;
    const int m0 = blockIdx.x * 64;
    const int n0 = blockIdx.y * 128;
    const int tid  = threadIdx.x;
    const int wave = tid >> 6;
    const int lane = tid & 63;
    const int wm = (wave >> 1) * 32;
    const int wn = (wave & 1) * 64;
    const int lrow = lane & 15;
    const int lk   = (lane >> 4) * 8;

    f32x4_t acc[2][4] = {};

#pragma unroll 4
    for (int ks = 0; ks < 512; ks += 32) {
        bf16x8_t af[2], wf[4];
#pragma unroll
        for (int mt = 0; mt < 2; ++mt)
            af[mt] = *(const bf16x8_t*)(A + (size_t)(m0 + wm + mt * 16 + lrow) * 512 + ks + lk);
#pragma unroll
        for (int nt = 0; nt < 4; ++nt)
            wf[nt] = *(const bf16x8_t*)(W + (size_t)(n0 + wn + nt * 16 + lrow) * 512 + ks + lk);
#pragma unroll
        for (int mt = 0; mt < 2; ++mt)
#pragma unroll
            for (int nt = 0; nt < 4; ++nt)
                acc[mt][nt] = MFMA16(wf[nt], af[mt], acc[mt][nt]);  // D[n][m]
    }

    const int g4 = (lane >> 4) * 4;
#pragma unroll
    for (int mt = 0; mt < 2; ++mt) {
        const int m  = m0 + wm + mt * 16 + lrow;   // output row (b,l)
        const int bb = m >> 11;
        const int l  = m & 2047;
#pragma unroll
        for (int nt = 0; nt < 4; ++nt) {
            const int nb = n0 + wn + nt * 16 + g4;  // 4 consecutive n
            const int h  = nb >> 6;
            const int d  = nb & 63;                 // d..d+3 same head
            const size_t idx = ((size_t)(bb * 8 + h) * 2048 + l) * 64 + d;
            const f32x4_t v = acc[mt][nt];
            s16x4_t pb;
            pb[0] = f2bf(v[0]); pb[1] = f2bf(v[1]);
            pb[2] = f2bf(v[2]); pb[3] = f2bf(v[3]);
            if (z == 0) {
                *(f32x4_t*)(qh_f32 + idx) = v;
                *(s16x4_t*)(qh_bf + idx) = pb;
            } else {
                *(s16x4_t*)(kh_bf + idx) = pb;
            }
        }
    }
}

// ---------------------------------------------------------------------------
// Kernel 2a: row sums only -> rinv[b,h,row]. grid (64,16): x = 32-row q tile,
// y = (b,h) so consecutive blocks share one K panel (L2 locality).
// ---------------------------------------------------------------------------
__global__ __launch_bounds__(256) void sum_kernel(
    const short* __restrict__ qh, const short* __restrict__ kh,
    const int* __restrict__ mask, float* __restrict__ rinv_g)
{
    const int q0 = blockIdx.x * 32;
    const int bh = blockIdx.y;
    const int b  = bh >> 3;
    const int tid = threadIdx.x;

    __shared__ float bias[2048];
    __shared__ float psum[4 * 32];

    for (int j = tid; j < 2048; j += 256)
        bias[j] = mask[b * 2048 + j] ? 0.f : -1e9f;
    __syncthreads();

    const int wave = tid >> 6;
    const int lane = tid & 63;
    const int lrow = lane & 15;
    const int lk   = (lane >> 4) * 8;
    const int g4   = (lane >> 4) * 4;

    const short* Qb = qh + (size_t)bh * 2048 * 64;
    const short* Kb = kh + (size_t)bh * 2048 * 64;

    bf16x8_t qf0[2], qf1[2];
#pragma unroll
    for (int rt = 0; rt < 2; ++rt) {
        const short* qp = Qb + (size_t)(q0 + rt * 16 + lrow) * 64 + lk;
        qf0[rt] = *(const bf16x8_t*)qp;
        qf1[rt] = *(const bf16x8_t*)(qp + 32);
    }

    const int k0 = wave * 512;
    float sum[2] = {0.f, 0.f};
#pragma unroll 4
    for (int kc = k0; kc < k0 + 512; kc += 16) {
        const short* kp = Kb + (size_t)(kc + lrow) * 64 + lk;
        const bf16x8_t ka = *(const bf16x8_t*)kp;
        const bf16x8_t kb2 = *(const bf16x8_t*)(kp + 32);
        const f32x4_t b4 = *(const f32x4_t*)&bias[kc + g4];
#pragma unroll
        for (int rt = 0; rt < 2; ++rt) {
            f32x4_t acc = {};
            acc = MFMA16(ka,  qf0[rt], acc);   // D[key][qrow]
            acc = MFMA16(kb2, qf1[rt], acc);
#pragma unroll
            for (int r = 0; r < 4; ++r)
                sum[rt] += __expf(fmaf(acc[r], 0.125f, b4[r]));
        }
    }
#pragma unroll
    for (int rt = 0; rt < 2; ++rt) {
        sum[rt] += __shfl_xor(sum[rt], 16, 64);
        sum[rt] += __shfl_xor(sum[rt], 32, 64);
    }
    if (lane < 16) {
        psum[wave * 32 + lane]      = sum[0];
        psum[wave * 32 + 16 + lane] = sum[1];
    }
    __syncthreads();
    if (tid < 32)
        rinv_g[bh * 2048 + q0 + tid] =
            1.f / (psum[tid] + psum[32 + tid] + psum[64 + tid] + psum[96 + tid]);
}

// ---------------------------------------------------------------------------
// Kernel 2b: recompute scores, scale by rinv, stage 16x64 fp32 chunks in
// wave-private LDS, then store LINEARLY: each global store instruction covers
// 4 consecutive rows x 256 B contiguous (2 full cache lines per row) — no
// 64 B partial-line scatter streams. grid (64,16): block = 32 q-rows;
// wave = 16-row half x 1024-key half. LDS 8K bias + 17.4K stage.
// ---------------------------------------------------------------------------
__global__ __launch_bounds__(256) void write_kernel(
    const short* __restrict__ qh, const short* __restrict__ kh,
    const int* __restrict__ mask, const float* __restrict__ rinv_g,
    float* __restrict__ attn)
{
    const int q0 = blockIdx.x * 32;
    const int bh = blockIdx.y;
    const int b  = bh >> 3;
    const int tid = threadIdx.x;

    __shared__ float bias[2048];
    __shared__ float stg[4][16 * 68];   // per-wave 16 rows x 68 cols fp32

    for (int j = tid; j < 2048; j += 256)
        bias[j] = mask[b * 2048 + j] ? 0.f : -1e9f;
    __syncthreads();

    const int wave = tid >> 6;
    const int lane = tid & 63;
    const int lrow = lane & 15;
    const int lk   = (lane >> 4) * 8;
    const int g4   = (lane >> 4) * 4;

    const int rh = (wave >> 1) * 16;    // row-half offset within block
    const int k0 = (wave & 1) * 1024;   // key-half

    const short* Qb = qh + (size_t)bh * 2048 * 64;
    const short* Kb = kh + (size_t)bh * 2048 * 64;

    const short* qp = Qb + (size_t)(q0 + rh + lrow) * 64 + lk;
    const bf16x8_t qf0 = *(const bf16x8_t*)qp;
    const bf16x8_t qf1 = *(const bf16x8_t*)(qp + 32);
    const float rv = rinv_g[bh * 2048 + q0 + rh + lrow];

    float* wst = stg[wave];
    float* outb = attn + ((size_t)bh * 2048 + q0 + rh) * 2048;

    for (int c0 = k0; c0 < k0 + 1024; c0 += 64) {
        // compute 16 rows x 64 keys, exp-normalized, into wave-private LDS
#pragma unroll
        for (int s = 0; s < 4; ++s) {
            const int kc = c0 + s * 16;
            const short* kp = Kb + (size_t)(kc + lrow) * 64 + lk;
            const bf16x8_t ka  = *(const bf16x8_t*)kp;
            const bf16x8_t kb2 = *(const bf16x8_t*)(kp + 32);
            const f32x4_t b4 = *(const f32x4_t*)&bias[kc + g4];
            f32x4_t acc = {};
            acc = MFMA16(ka,  qf0, acc);   // D[key][qrow]: lane = qrow lrow, keys kc+g4+r
            acc = MFMA16(kb2, qf1, acc);
            f32x4_t o;
#pragma unroll
            for (int r = 0; r < 4; ++r)
                o[r] = __expf(fmaf(acc[r], 0.125f, b4[r])) * rv;
            *(f32x4_t*)&wst[lrow * 68 + s * 16 + g4] = o;
        }
        // wave-synchronous LDS readback -> linear stores:
        // instruction = rows {rr*4..rr*4+3} x 256 B contiguous each
#pragma unroll
        for (int rr = 0; rr < 4; ++rr) {
            const int row = rr * 4 + (lane >> 4);
            const f32x4_t v = *(const f32x4_t*)&wst[row * 68 + lrow * 4];
            *(f32x4_t*)(outb + (size_t)row * 2048 + c0 + lrow * 4) = v;
        }
    }
}

// ---------------------------------------------------------------------------
extern "C" void kernel_launch(void* const* d_in, const int* in_sizes, int n_in,
                              void* d_out, int out_size, void* d_ws, size_t ws_size,
                              hipStream_t stream)
{
    const float* q    = (const float*)d_in[0];
    const float* k    = (const float*)d_in[1];
    const int*   mask = (const int*)  d_in[3];
    const float* Wq   = (const float*)d_in[4];
    const float* Wk   = (const float*)d_in[5];

    float* out    = (float*)d_out;
    float* qh_f32 = out;                 // 2,097,152 floats
    float* attn   = out + 2097152;       // 67,108,864 floats

    short* qh_bf = (short*)d_ws;         // 4 MB
    short* kh_bf = qh_bf + 2097152;      // 4 MB
    float* rinv  = (float*)(kh_bf + 2097152);  // 128 KB

    // bf16 input scratch lives in the not-yet-written attn output region
    // (consumed by proj_kernel before attn writes start).
    short* qb  = (short*)attn;
    short* kb  = qb  + 2097152;
    short* Wqb = kb  + 2097152;
    short* Wkb = Wqb + 262144;

    cvt_kernel  <<<dim3(1024),     256, 0, stream>>>(q, k, Wq, Wk, qb, kb, Wqb, Wkb);
    proj_kernel <<<dim3(64, 4, 2), 256, 0, stream>>>(qb, kb, Wqb, Wkb, qh_f32, qh_bf, kh_bf);
    sum_kernel  <<<dim3(64, 16),   256, 0, stream>>>(qh_bf, kh_bf, mask, rinv);
    write_kernel<<<dim3(64, 16),   256, 0, stream>>>(qh_bf, kh_bf, mask, rinv, attn);
}

// Round 5
// 390.373 us; speedup vs baseline: 1.0257x; 1.0212x over previous
//
#include <hip/hip_runtime.h>

// Problem constants: B=2, L=2048, NH=8, DH=64, DM=512, TEMP=8.
// Outputs (concat fp32): qh (2,8,2048,64) then attn (2,8,2048,2048).

typedef __attribute__((ext_vector_type(8))) short bf16x8_t;   // MFMA A/B frag
typedef __attribute__((ext_vector_type(4))) float f32x4_t;    // MFMA C/D frag
typedef __attribute__((ext_vector_type(4))) short s16x4_t;

#define MFMA16(a, b, c) __builtin_amdgcn_mfma_f32_16x16x32_bf16((a), (b), (c), 0, 0, 0)

__device__ __forceinline__ short f2bf(float x) {
    union { float f; unsigned u; } v; v.f = x;
    unsigned r = v.u + 0x7fffu + ((v.u >> 16) & 1u);
    return (short)(r >> 16);
}

// ---------------------------------------------------------------------------
// Kernel 0: fp32 -> bf16 convert of q, k, Wq, Wk — each element exactly once.
// ---------------------------------------------------------------------------
__global__ __launch_bounds__(256) void cvt_kernel(
    const float* __restrict__ q, const float* __restrict__ k,
    const float* __restrict__ Wq, const float* __restrict__ Wk,
    short* __restrict__ qb, short* __restrict__ kb,
    short* __restrict__ Wqb, short* __restrict__ Wkb)
{
    const int NQ = 262144;   // 2*2048*512 / 8 vec8 chunks
    const int NW = 32768;    // 512*512 / 8
    for (int i = blockIdx.x * 256 + threadIdx.x; i < 2 * NQ + 2 * NW;
         i += gridDim.x * 256) {
        const float* src; short* dst; int off;
        if (i < NQ)               { src = q;  dst = qb;  off = i; }
        else if (i < 2 * NQ)      { src = k;  dst = kb;  off = i - NQ; }
        else if (i < 2 * NQ + NW) { src = Wq; dst = Wqb; off = i - 2 * NQ; }
        else                      { src = Wk; dst = Wkb; off = i - 2 * NQ - NW; }
        const float* p = src + (size_t)off * 8;
        f32x4_t lo = *(const f32x4_t*)p;
        f32x4_t hi = *(const f32x4_t*)(p + 4);
        bf16x8_t r;
        r[0] = f2bf(lo[0]); r[1] = f2bf(lo[1]); r[2] = f2bf(lo[2]); r[3] = f2bf(lo[3]);
        r[4] = f2bf(hi[0]); r[5] = f2bf(hi[1]); r[6] = f2bf(hi[2]); r[7] = f2bf(hi[3]);
        *(bf16x8_t*)(dst + (size_t)off * 8) = r;
    }
}

// ---------------------------------------------------------------------------
// Kernel 1: C = A @ W^T for A in {q,k} bf16 (4096x512), W bf16 (512x512).
// Swapped operands: D[n][m], lane's 4 acc = 4 consecutive head-dims -> f32x4.
// qh_f32 is write-once (never re-read in-kernel) -> non-temporal stores so
// this stream doesn't evict the bf16 scratch from L2.
// ---------------------------------------------------------------------------
__global__ __launch_bounds__(256) void proj_kernel(
    const short* __restrict__ qb, const short* __restrict__ kb,
    const short* __restrict__ Wqb, const short* __restrict__ Wkb,
    float* __restrict__ qh_f32, short* __restrict__ qh_bf,
    short* __restrict__ kh_bf)
{
    const int z  = blockIdx.z;
    const short* A = z ? kb  : qb;
    const short* W = z ? Wkb : Wqb;
    const int m0 = blockIdx.x * 64;
    const int n0 = blockIdx.y * 128;
    const int tid  = threadIdx.x;
    const int wave = tid >> 6;
    const int lane = tid & 63;
    const int wm = (wave >> 1) * 32;
    const int wn = (wave & 1) * 64;
    const int lrow = lane & 15;
    const int lk   = (lane >> 4) * 8;

    f32x4_t acc[2][4] = {};

#pragma unroll 4
    for (int ks = 0; ks < 512; ks += 32) {
        bf16x8_t af[2], wf[4];
#pragma unroll
        for (int mt = 0; mt < 2; ++mt)
            af[mt] = *(const bf16x8_t*)(A + (size_t)(m0 + wm + mt * 16 + lrow) * 512 + ks + lk);
#pragma unroll
        for (int nt = 0; nt < 4; ++nt)
            wf[nt] = *(const bf16x8_t*)(W + (size_t)(n0 + wn + nt * 16 + lrow) * 512 + ks + lk);
#pragma unroll
        for (int mt = 0; mt < 2; ++mt)
#pragma unroll
            for (int nt = 0; nt < 4; ++nt)
                acc[mt][nt] = MFMA16(wf[nt], af[mt], acc[mt][nt]);  // D[n][m]
    }

    const int g4 = (lane >> 4) * 4;
#pragma unroll
    for (int mt = 0; mt < 2; ++mt) {
        const int m  = m0 + wm + mt * 16 + lrow;   // output row (b,l)
        const int bb = m >> 11;
        const int l  = m & 2047;
#pragma unroll
        for (int nt = 0; nt < 4; ++nt) {
            const int nb = n0 + wn + nt * 16 + g4;  // 4 consecutive n
            const int h  = nb >> 6;
            const int d  = nb & 63;                 // d..d+3 same head
            const size_t idx = ((size_t)(bb * 8 + h) * 2048 + l) * 64 + d;
            const f32x4_t v = acc[mt][nt];
            s16x4_t pb;
            pb[0] = f2bf(v[0]); pb[1] = f2bf(v[1]);
            pb[2] = f2bf(v[2]); pb[3] = f2bf(v[3]);
            if (z == 0) {
                __builtin_nontemporal_store(v, (f32x4_t*)(qh_f32 + idx));
                *(s16x4_t*)(qh_bf + idx) = pb;     // re-read by sum/write: cache
            } else {
                *(s16x4_t*)(kh_bf + idx) = pb;
            }
        }
    }
}

// ---------------------------------------------------------------------------
// Kernel 2a: row sums only -> rinv[b,h,row]. grid (64,16): x = 32-row q tile,
// y = (b,h) so x-neighbors share one K panel (L2 locality).
// ---------------------------------------------------------------------------
__global__ __launch_bounds__(256) void sum_kernel(
    const short* __restrict__ qh, const short* __restrict__ kh,
    const int* __restrict__ mask, float* __restrict__ rinv_g)
{
    const int q0 = blockIdx.x * 32;
    const int bh = blockIdx.y;
    const int b  = bh >> 3;
    const int tid = threadIdx.x;

    __shared__ float bias[2048];
    __shared__ float psum[4 * 32];

    for (int j = tid; j < 2048; j += 256)
        bias[j] = mask[b * 2048 + j] ? 0.f : -1e9f;
    __syncthreads();

    const int wave = tid >> 6;
    const int lane = tid & 63;
    const int lrow = lane & 15;
    const int lk   = (lane >> 4) * 8;
    const int g4   = (lane >> 4) * 4;

    const short* Qb = qh + (size_t)bh * 2048 * 64;
    const short* Kb = kh + (size_t)bh * 2048 * 64;

    bf16x8_t qf0[2], qf1[2];
#pragma unroll
    for (int rt = 0; rt < 2; ++rt) {
        const short* qp = Qb + (size_t)(q0 + rt * 16 + lrow) * 64 + lk;
        qf0[rt] = *(const bf16x8_t*)qp;
        qf1[rt] = *(const bf16x8_t*)(qp + 32);
    }

    const int k0 = wave * 512;
    float sum[2] = {0.f, 0.f};
#pragma unroll 4
    for (int kc = k0; kc < k0 + 512; kc += 16) {
        const short* kp = Kb + (size_t)(kc + lrow) * 64 + lk;
        const bf16x8_t ka = *(const bf16x8_t*)kp;
        const bf16x8_t kb2 = *(const bf16x8_t*)(kp + 32);
        const f32x4_t b4 = *(const f32x4_t*)&bias[kc + g4];
#pragma unroll
        for (int rt = 0; rt < 2; ++rt) {
            f32x4_t acc = {};
            acc = MFMA16(ka,  qf0[rt], acc);   // D[key][qrow]
            acc = MFMA16(kb2, qf1[rt], acc);
#pragma unroll
            for (int r = 0; r < 4; ++r)
                sum[rt] += __expf(fmaf(acc[r], 0.125f, b4[r]));
        }
    }
#pragma unroll
    for (int rt = 0; rt < 2; ++rt) {
        sum[rt] += __shfl_xor(sum[rt], 16, 64);
        sum[rt] += __shfl_xor(sum[rt], 32, 64);
    }
    if (lane < 16) {
        psum[wave * 32 + lane]      = sum[0];
        psum[wave * 32 + 16 + lane] = sum[1];
    }
    __syncthreads();
    if (tid < 32)
        rinv_g[bh * 2048 + q0 + tid] =
            1.f / (psum[tid] + psum[32 + tid] + psum[64 + tid] + psum[96 + tid]);
}

// ---------------------------------------------------------------------------
// Kernel 2b: recompute scores, scale by rinv, f32x4 NON-TEMPORAL stores.
// nt bypasses L2 allocation: the 268 MB store stream no longer evicts the
// (b,h) K panels, so K re-reads stay L2-resident instead of missing to HBM
// (~250 MB of avoided HBM fetch — the invariant cost all three previous
// store-pattern variants shared).
// grid (128,16): x = 16-row q tile, y = (b,h); 8 blocks/CU.
// ---------------------------------------------------------------------------
__global__ __launch_bounds__(256) void write_kernel(
    const short* __restrict__ qh, const short* __restrict__ kh,
    const int* __restrict__ mask, const float* __restrict__ rinv_g,
    float* __restrict__ attn)
{
    const int q0 = blockIdx.x * 16;
    const int bh = blockIdx.y;
    const int b  = bh >> 3;
    const int tid = threadIdx.x;

    __shared__ float bias[2048];

    for (int j = tid; j < 2048; j += 256)
        bias[j] = mask[b * 2048 + j] ? 0.f : -1e9f;
    __syncthreads();

    const int wave = tid >> 6;
    const int lane = tid & 63;
    const int lrow = lane & 15;
    const int lk   = (lane >> 4) * 8;
    const int g4   = (lane >> 4) * 4;

    const short* Qb = qh + (size_t)bh * 2048 * 64;
    const short* Kb = kh + (size_t)bh * 2048 * 64;

    const short* qp = Qb + (size_t)(q0 + lrow) * 64 + lk;
    const bf16x8_t qf0 = *(const bf16x8_t*)qp;
    const bf16x8_t qf1 = *(const bf16x8_t*)(qp + 32);
    const float rv = rinv_g[bh * 2048 + q0 + lrow];

    const int k0 = wave * 512;
    // lane's store base: its q row, its 4-key group
    float* orow = attn + ((size_t)bh * 2048 + q0 + lrow) * 2048 + g4;

#pragma unroll 4
    for (int kc = k0; kc < k0 + 512; kc += 16) {
        const short* kp = Kb + (size_t)(kc + lrow) * 64 + lk;
        const bf16x8_t ka = *(const bf16x8_t*)kp;
        const bf16x8_t kb2 = *(const bf16x8_t*)(kp + 32);
        const f32x4_t b4 = *(const f32x4_t*)&bias[kc + g4];
        f32x4_t acc = {};
        acc = MFMA16(ka,  qf0, acc);   // D[key][qrow]
        acc = MFMA16(kb2, qf1, acc);
        f32x4_t o;
#pragma unroll
        for (int r = 0; r < 4; ++r)
            o[r] = __expf(fmaf(acc[r], 0.125f, b4[r])) * rv;
        __builtin_nontemporal_store(o, (f32x4_t*)(orow + kc));
    }
}

// ---------------------------------------------------------------------------
extern "C" void kernel_launch(void* const* d_in, const int* in_sizes, int n_in,
                              void* d_out, int out_size, void* d_ws, size_t ws_size,
                              hipStream_t stream)
{
    const float* q    = (const float*)d_in[0];
    const float* k    = (const float*)d_in[1];
    const int*   mask = (const int*)  d_in[3];
    const float* Wq   = (const float*)d_in[4];
    const float* Wk   = (const float*)d_in[5];

    float* out    = (float*)d_out;
    float* qh_f32 = out;                 // 2,097,152 floats
    float* attn   = out + 2097152;       // 67,108,864 floats

    short* qh_bf = (short*)d_ws;         // 4 MB
    short* kh_bf = qh_bf + 2097152;      // 4 MB
    float* rinv  = (float*)(kh_bf + 2097152);  // 128 KB

    // bf16 input scratch lives in the not-yet-written attn output region
    // (consumed by proj_kernel before attn writes start).
    short* qb  = (short*)attn;
    short* kb  = qb  + 2097152;
    short* Wqb = kb  + 2097152;
    short* Wkb = Wqb + 262144;

    cvt_kernel  <<<dim3(1024),     256, 0, stream>>>(q, k, Wq, Wk, qb, kb, Wqb, Wkb);
    proj_kernel <<<dim3(64, 4, 2), 256, 0, stream>>>(qb, kb, Wqb, Wkb, qh_f32, qh_bf, kh_bf);
    sum_kernel  <<<dim3(64, 16),   256, 0, stream>>>(qh_bf, kh_bf, mask, rinv);
    write_kernel<<<dim3(128, 16),  256, 0, stream>>>(qh_bf, kh_bf, mask, rinv, attn);
}

// Round 6
// 385.347 us; speedup vs baseline: 1.0390x; 1.0130x over previous
//
#include <hip/hip_runtime.h>

// Problem constants: B=2, L=2048, NH=8, DH=64, DM=512, TEMP=8.
// Outputs (concat fp32): qh (2,8,2048,64) then attn (2,8,2048,2048).

typedef __attribute__((ext_vector_type(8))) short bf16x8_t;   // MFMA A/B frag
typedef __attribute__((ext_vector_type(4))) float f32x4_t;    // MFMA C/D frag
typedef __attribute__((ext_vector_type(4))) short s16x4_t;

#define MFMA16(a, b, c) __builtin_amdgcn_mfma_f32_16x16x32_bf16((a), (b), (c), 0, 0, 0)

__device__ __forceinline__ short f2bf(float x) {
    union { float f; unsigned u; } v; v.f = x;
    unsigned r = v.u + 0x7fffu + ((v.u >> 16) & 1u);
    return (short)(r >> 16);
}
__device__ __forceinline__ unsigned pack2bf(float a, float b) {
    return ((unsigned)(unsigned short)f2bf(a)) |
           (((unsigned)(unsigned short)f2bf(b)) << 16);
}
__device__ __forceinline__ float lo2f(unsigned u) {
    union { float f; unsigned u; } v; v.u = u << 16; return v.f;
}
__device__ __forceinline__ float hi2f(unsigned u) {
    union { float f; unsigned u; } v; v.u = u & 0xffff0000u; return v.f;
}

// ---------------------------------------------------------------------------
// Kernel 0: fp32 -> bf16 convert of q, k, Wq, Wk — each element exactly once.
// ---------------------------------------------------------------------------
__global__ __launch_bounds__(256) void cvt_kernel(
    const float* __restrict__ q, const float* __restrict__ k,
    const float* __restrict__ Wq, const float* __restrict__ Wk,
    short* __restrict__ qb, short* __restrict__ kb,
    short* __restrict__ Wqb, short* __restrict__ Wkb)
{
    const int NQ = 262144;   // 2*2048*512 / 8 vec8 chunks
    const int NW = 32768;    // 512*512 / 8
    for (int i = blockIdx.x * 256 + threadIdx.x; i < 2 * NQ + 2 * NW;
         i += gridDim.x * 256) {
        const float* src; short* dst; int off;
        if (i < NQ)               { src = q;  dst = qb;  off = i; }
        else if (i < 2 * NQ)      { src = k;  dst = kb;  off = i - NQ; }
        else if (i < 2 * NQ + NW) { src = Wq; dst = Wqb; off = i - 2 * NQ; }
        else                      { src = Wk; dst = Wkb; off = i - 2 * NQ - NW; }
        const float* p = src + (size_t)off * 8;
        f32x4_t lo = *(const f32x4_t*)p;
        f32x4_t hi = *(const f32x4_t*)(p + 4);
        bf16x8_t r;
        r[0] = f2bf(lo[0]); r[1] = f2bf(lo[1]); r[2] = f2bf(lo[2]); r[3] = f2bf(lo[3]);
        r[4] = f2bf(hi[0]); r[5] = f2bf(hi[1]); r[6] = f2bf(hi[2]); r[7] = f2bf(hi[3]);
        *(bf16x8_t*)(dst + (size_t)off * 8) = r;
    }
}

// ---------------------------------------------------------------------------
// Kernel 1: C = A @ W^T for A in {q,k} bf16 (4096x512), W bf16 (512x512).
// Swapped operands: D[n][m], lane's 4 acc = 4 consecutive head-dims -> f32x4.
// ---------------------------------------------------------------------------
__global__ __launch_bounds__(256) void proj_kernel(
    const short* __restrict__ qb, const short* __restrict__ kb,
    const short* __restrict__ Wqb, const short* __restrict__ Wkb,
    float* __restrict__ qh_f32, short* __restrict__ qh_bf,
    short* __restrict__ kh_bf)
{
    const int z  = blockIdx.z;
    const short* A = z ? kb  : qb;
    const short* W = z ? Wkb : Wqb;
    const int m0 = blockIdx.x * 64;
    const int n0 = blockIdx.y * 128;
    const int tid  = threadIdx.x;
    const int wave = tid >> 6;
    const int lane = tid & 63;
    const int wm = (wave >> 1) * 32;
    const int wn = (wave & 1) * 64;
    const int lrow = lane & 15;
    const int lk   = (lane >> 4) * 8;

    f32x4_t acc[2][4] = {};

#pragma unroll 4
    for (int ks = 0; ks < 512; ks += 32) {
        bf16x8_t af[2], wf[4];
#pragma unroll
        for (int mt = 0; mt < 2; ++mt)
            af[mt] = *(const bf16x8_t*)(A + (size_t)(m0 + wm + mt * 16 + lrow) * 512 + ks + lk);
#pragma unroll
        for (int nt = 0; nt < 4; ++nt)
            wf[nt] = *(const bf16x8_t*)(W + (size_t)(n0 + wn + nt * 16 + lrow) * 512 + ks + lk);
#pragma unroll
        for (int mt = 0; mt < 2; ++mt)
#pragma unroll
            for (int nt = 0; nt < 4; ++nt)
                acc[mt][nt] = MFMA16(wf[nt], af[mt], acc[mt][nt]);  // D[n][m]
    }

    const int g4 = (lane >> 4) * 4;
#pragma unroll
    for (int mt = 0; mt < 2; ++mt) {
        const int m  = m0 + wm + mt * 16 + lrow;   // output row (b,l)
        const int bb = m >> 11;
        const int l  = m & 2047;
#pragma unroll
        for (int nt = 0; nt < 4; ++nt) {
            const int nb = n0 + wn + nt * 16 + g4;  // 4 consecutive n
            const int h  = nb >> 6;
            const int d  = nb & 63;                 // d..d+3 same head
            const size_t idx = ((size_t)(bb * 8 + h) * 2048 + l) * 64 + d;
            const f32x4_t v = acc[mt][nt];
            s16x4_t pb;
            pb[0] = f2bf(v[0]); pb[1] = f2bf(v[1]);
            pb[2] = f2bf(v[2]); pb[3] = f2bf(v[3]);
            if (z == 0) {
                __builtin_nontemporal_store(v, (f32x4_t*)(qh_f32 + idx));
                *(s16x4_t*)(qh_bf + idx) = pb;     // re-read by attn: cache
            } else {
                *(s16x4_t*)(kh_bf + idx) = pb;
            }
        }
    }
}

// ---------------------------------------------------------------------------
// Kernel 2: fused single-pass attn with REGISTER staging of exp values.
// Scores computed ONCE (R2-R5 computed them twice); no pass-2 K reads; no
// 74 KB LDS (R0's occupancy limiter). Block = 16 q-rows x 2048 keys,
// 512 threads = 8 waves x 256-key slice. Each lane owns 64 scores for its
// one q-row, packed bf16 in 32 VGPRs (fully unrolled -> static indexing,
// stays in registers). Pass 1: MFMA+exp+pack, fp32 row sums. Block reduce
// rinv. Pass 2: unpack, scale, nt f32x4 store (wave inst = 16 rows x 64 B;
// unroll covers 256 B/row). ~80 VGPR -> ~3 blocks/CU: stores of one block
// overlap compute of two others.
// grid (128, 16): x = q-tile (x-neighbors share the bh K panel in L2).
// ---------------------------------------------------------------------------
__global__ __launch_bounds__(512) void attn_kernel(
    const short* __restrict__ qh, const short* __restrict__ kh,
    const int* __restrict__ mask, float* __restrict__ attn)
{
    const int q0 = blockIdx.x * 16;
    const int bh = blockIdx.y;
    const int b  = bh >> 3;
    const int tid = threadIdx.x;

    __shared__ float bias[2048];     // 8 KB
    __shared__ float psum[8 * 16];
    __shared__ float rinvs[16];

    for (int j = tid; j < 2048; j += 512)
        bias[j] = mask[b * 2048 + j] ? 0.f : -1e9f;
    __syncthreads();

    const int wave = tid >> 6;
    const int lane = tid & 63;
    const int lrow = lane & 15;
    const int lk   = (lane >> 4) * 8;
    const int g4   = (lane >> 4) * 4;

    const short* Qb = qh + (size_t)bh * 2048 * 64;
    const short* Kb = kh + (size_t)bh * 2048 * 64;

    const short* qp = Qb + (size_t)(q0 + lrow) * 64 + lk;
    const bf16x8_t qf0 = *(const bf16x8_t*)qp;
    const bf16x8_t qf1 = *(const bf16x8_t*)(qp + 32);

    const int k0 = wave * 256;       // wave's 256-key slice

    // ---- pass 1: scores -> exp -> packed bf16 registers + row sum ----
    unsigned stg[32];
    float sum = 0.f;
#pragma unroll
    for (int it = 0; it < 16; ++it) {
        const int kc = k0 + it * 16;
        const short* kp = Kb + (size_t)(kc + lrow) * 64 + lk;
        const bf16x8_t ka  = *(const bf16x8_t*)kp;
        const bf16x8_t kb2 = *(const bf16x8_t*)(kp + 32);
        const f32x4_t b4 = *(const f32x4_t*)&bias[kc + g4];
        f32x4_t acc = {};
        acc = MFMA16(ka,  qf0, acc);   // D[key][qrow]: lane = qrow lrow, keys kc+g4+r
        acc = MFMA16(kb2, qf1, acc);
        const float e0 = __expf(fmaf(acc[0], 0.125f, b4[0]));
        const float e1 = __expf(fmaf(acc[1], 0.125f, b4[1]));
        const float e2 = __expf(fmaf(acc[2], 0.125f, b4[2]));
        const float e3 = __expf(fmaf(acc[3], 0.125f, b4[3]));
        sum += (e0 + e1) + (e2 + e3);
        stg[2 * it]     = pack2bf(e0, e1);
        stg[2 * it + 1] = pack2bf(e2, e3);
    }
    // fold the 4 key-groups (lanes sharing lrow): xor 16, 32
    sum += __shfl_xor(sum, 16, 64);
    sum += __shfl_xor(sum, 32, 64);
    if (lane < 16)
        psum[wave * 16 + lane] = sum;
    __syncthreads();
    if (tid < 16) {
        float s = psum[tid];
#pragma unroll
        for (int w = 1; w < 8; ++w)
            s += psum[w * 16 + tid];
        rinvs[tid] = 1.f / s;
    }
    __syncthreads();
    const float rv = rinvs[lrow];

    // ---- pass 2: unpack, scale, nt store (no recompute, no K reads) ----
    float* orow = attn + ((size_t)bh * 2048 + q0 + lrow) * 2048 + g4;
#pragma unroll
    for (int it = 0; it < 16; ++it) {
        const unsigned u0 = stg[2 * it];
        const unsigned u1 = stg[2 * it + 1];
        f32x4_t o;
        o[0] = lo2f(u0) * rv;
        o[1] = hi2f(u0) * rv;
        o[2] = lo2f(u1) * rv;
        o[3] = hi2f(u1) * rv;
        __builtin_nontemporal_store(o, (f32x4_t*)(orow + k0 + it * 16));
    }
}

// ---------------------------------------------------------------------------
extern "C" void kernel_launch(void* const* d_in, const int* in_sizes, int n_in,
                              void* d_out, int out_size, void* d_ws, size_t ws_size,
                              hipStream_t stream)
{
    const float* q    = (const float*)d_in[0];
    const float* k    = (const float*)d_in[1];
    const int*   mask = (const int*)  d_in[3];
    const float* Wq   = (const float*)d_in[4];
    const float* Wk   = (const float*)d_in[5];

    float* out    = (float*)d_out;
    float* qh_f32 = out;                 // 2,097,152 floats
    float* attn   = out + 2097152;       // 67,108,864 floats

    short* qh_bf = (short*)d_ws;         // 4 MB
    short* kh_bf = qh_bf + 2097152;      // 4 MB

    // bf16 input scratch lives in the not-yet-written attn output region
    // (consumed by proj_kernel before attn writes start).
    short* qb  = (short*)attn;
    short* kb  = qb  + 2097152;
    short* Wqb = kb  + 2097152;
    short* Wkb = Wqb + 262144;

    cvt_kernel <<<dim3(1024),     256, 0, stream>>>(q, k, Wq, Wk, qb, kb, Wqb, Wkb);
    proj_kernel<<<dim3(64, 4, 2), 256, 0, stream>>>(qb, kb, Wqb, Wkb, qh_f32, qh_bf, kh_bf);
    attn_kernel<<<dim3(128, 16),  512, 0, stream>>>(qh_bf, kh_bf, mask, attn);
}